// Round 13
// baseline (150.926 us; speedup 1.0000x reference)
//
#include <hip/hip_runtime.h>
#include <math.h>

#define B_N 2048
#define D_FT 784
#define K_N 50
#define L_N 6
#define LOG2PI_F 1.8378770664093453f

// ---- output layout (floats), concatenated in reference return order ----
#define OUT_PW 0
#define OUT_M  (B_N)                              // 2048
#define OUT_A  (OUT_M + B_N*D_FT)                 // 1607680
#define OUT_D  (OUT_A + B_N*D_FT*6)               // 11241472

// ---- workspace layout (float offsets) ----
#define WS_SCORES 0                                // [K][B] (pre-accum: SJL jld terms)
#define WS_PQ     (WS_SCORES + K_N*B_N)            // [K][27][B] 2764800
#define WS_XT     (WS_PQ + K_N*27*B_N)             // [D/4][B] float4 = D*B floats
#define WS_JBT    (WS_XT + D_FT*B_N)               // [25][B]    51200

#define IDX(i,j) ((i)*((i)+1)/2 + (j))   // packed lower, i>=j

typedef float v2f __attribute__((ext_vector_type(2)));

// VOP3P packed f32: 2 f32 ops/inst (4 cyc/wave64 on SIMD32 — NOT rate-doubling
// vs scalar fma; the win is issue-slot halving on non-FMA overhead).
#define PK_FMA(acc, a, b) asm("v_pk_fma_f32 %0, %1, %2, %0" : "+v"(acc) : "v"(a), "v"(b))
#define PK_MUL(dst, a, b) asm("v_pk_mul_f32 %0, %1, %2" : "=v"(dst) : "v"(a), "v"(b))
#define PK_ADD(dst, a, b) asm("v_pk_add_f32 %0, %1, %2" : "=v"(dst) : "v"(a), "v"(b))

// ---------- 6x6 packed-lower Cholesky ----------
__device__ __forceinline__ void chol6(const float* P, float* L, float* rd, float* sumlog) {
    float sl = 0.f;
    #pragma unroll
    for (int j = 0; j < 6; ++j) {
        float s = P[IDX(j,j)];
        #pragma unroll
        for (int m = 0; m < j; ++m) s -= L[IDX(j,m)] * L[IDX(j,m)];
        float d = sqrtf(s);
        L[IDX(j,j)] = d;
        float r = 1.0f / d;
        rd[j] = r;
        sl += logf(d);
        #pragma unroll
        for (int i = j + 1; i < 6; ++i) {
            float t = P[IDX(i,j)];
            #pragma unroll
            for (int m = 0; m < j; ++m) t -= L[IDX(i,m)] * L[IDX(j,m)];
            L[IDX(i,j)] = t * r;
        }
    }
    *sumlog = sl;
}

// ---------- K0: fused transpose (X -> Xt4) + packbits (J -> JbT) ----------
__global__ __launch_bounds__(1024) void k_prep(const float* __restrict__ X,
                                               const int* __restrict__ J,
                                               float4* __restrict__ Xt4,
                                               unsigned* __restrict__ JbT) {
    const int bid = blockIdx.x;
    const int tid = threadIdx.x;
    if (bid < 448) {
        __shared__ float4 tile[32][33];
        int tx = tid & 31, ty = tid >> 5;
        int d4b = (bid % 7) * 32;
        int bb  = (bid / 7) * 32;
        int d4 = d4b + tx;
        if (d4 < D_FT / 4)
            tile[ty][tx] = *(const float4*)&X[(size_t)(bb + ty) * D_FT + d4 * 4];
        __syncthreads();
        int d4o = d4b + ty;
        if (d4o < D_FT / 4)
            Xt4[(size_t)d4o * B_N + (bb + tx)] = tile[tx][ty];
    } else {
        int t = (bid - 448) * 1024 + tid;    // 65536 threads = 2048 b x 32 w
        int b = t >> 5;
        int w = t & 31;
        if (w >= 25) return;
        int d0 = w * 32;
        int n = D_FT - d0; if (n > 32) n = 32;
        unsigned u = 0;
        for (int j = 0; j < n; ++j)
            u |= (J[(size_t)b * D_FT + d0 + j] != 0 ? 1u : 0u) << j;
        JbT[(size_t)w * B_N + b] = u;
    }
}

// ---------- K0c: SJL[k][b] = sum_d Jf[b,d]*logD[k,d]  (into scores buffer) ----------
__global__ __launch_bounds__(256) void k_jld(const float* __restrict__ logD,
                                             const unsigned* __restrict__ JbT,
                                             float* __restrict__ SJL) {
    __shared__ float ld[800];
    const int k  = blockIdx.x >> 3;
    const int bt = blockIdx.x & 7;
    for (int i = threadIdx.x; i < 800; i += 256)
        ld[i] = (i < D_FT) ? logD[(size_t)k * D_FT + i] : 0.f;
    __syncthreads();
    const int b = bt * 256 + threadIdx.x;
    float jl0 = 0.f, jl1 = 0.f;
    for (int w = 0; w < 25; ++w) {
        unsigned mw = JbT[(size_t)w * B_N + b];
        const float* lw = &ld[w * 32];
        #pragma unroll
        for (int dd = 0; dd < 32; dd += 2) {
            jl0 += ((mw >> dd) & 1u) ? lw[dd] : 0.f;
            jl1 += ((mw >> (dd + 1)) & 1u) ? lw[dd + 1] : 0.f;
        }
    }
    SJL[(size_t)k * B_N + b] = jl0 + jl1;
}

// ---------- epilogue: P -> chol -> loglik -> score + Pq store ----------
__device__ __forceinline__ void epilogue(float* Pm, float* qv, float quad, float nobs,
                                         int k, int b, const float* __restrict__ PI,
                                         float* __restrict__ scores,
                                         float* __restrict__ Pq) {
    float jld = scores[(size_t)k * B_N + b];   // SJL precomputed by k_jld

    Pm[0] += 1.f; Pm[2] += 1.f; Pm[5] += 1.f; Pm[9] += 1.f; Pm[14] += 1.f; Pm[20] += 1.f;

    float Lm[21], rd[6], sumlog;
    chol6(Pm, Lm, rd, &sumlog);
    float y[6];
    #pragma unroll
    for (int j = 0; j < 6; ++j) {
        float sv = qv[j];
        #pragma unroll
        for (int m = 0; m < j; ++m) sv -= Lm[IDX(j,m)] * y[m];
        y[j] = sv * rd[j];
    }
    float yy = 0.f;
    #pragma unroll
    for (int j = 0; j < 6; ++j) yy += y[j] * y[j];
    float logdet = 2.f * sumlog + jld;
    float ll = -0.5f * ((quad - yy) + logdet + nobs * LOG2PI_F);
    float score = ll + PI[k];

    scores[(size_t)k * B_N + b] = score;
    float* pq = Pq + (size_t)k * 27 * B_N + b;
    #pragma unroll
    for (int t = 0; t < 21; ++t) pq[(size_t)t * B_N] = Pm[t];
    #pragma unroll
    for (int t = 0; t < 6; ++t) pq[(size_t)(21 + t) * B_N] = qv[t];
}

// ---------- K1: per-(sample,k) accumulation, TWO samples per thread ----------
// 256 threads = 64 lanes x 4 d-quarters; each thread owns samples b0 and
// b0+64 -> each 64 B record read feeds 2x the math, halving LDS return-path
// bandwidth (r12 diagnosis: LDS writeback saturated at ~130% of CU capacity
// with 1 sample/thread; broadcast does NOT discount the 64-lane writeback).
// Record = 8 v2f slots/pair (64 B): a0..a5 raw pairs, invD pair, -mu pair.
// Math (== reference order): w = m*invD; z = x-mu; t = w*z;
//   P_ij += (w*a_i)*a_j; q_j += t*a_j; quad += t*z.
// launch_bounds(256,3): allocator accepts >64 VGPR without spill here (r11:
// 80 clean); (256,4) pins at 64 and spills (r9); min-waves>=6 catastrophic
// (r3/r4). Records must be LDS-resident (r7: global -> +24 us VMEM latency).
#define ACC_PAIR2(pi, dd, xa0, xa1, xb0, xb1) do { \
    const v2f a0 = srec[(size_t)(pi) * 8 + 0]; \
    const v2f a1 = srec[(size_t)(pi) * 8 + 1]; \
    const v2f a2 = srec[(size_t)(pi) * 8 + 2]; \
    const v2f a3 = srec[(size_t)(pi) * 8 + 3]; \
    const v2f a4 = srec[(size_t)(pi) * 8 + 4]; \
    const v2f a5 = srec[(size_t)(pi) * 8 + 5]; \
    const v2f iD2  = srec[(size_t)(pi) * 8 + 6]; \
    const v2f nmu2 = srec[(size_t)(pi) * 8 + 7]; \
    v2f ma2; ma2.x = (float)((mwa >> (dd)) & 1u); ma2.y = (float)((mwa >> ((dd)+1)) & 1u); \
    v2f mb2; mb2.x = (float)((mwb >> (dd)) & 1u); mb2.y = (float)((mwb >> ((dd)+1)) & 1u); \
    v2f xa2; xa2.x = (xa0); xa2.y = (xa1); \
    v2f xb2; xb2.x = (xb0); xb2.y = (xb1); \
    v2f za2; PK_ADD(za2, xa2, nmu2); \
    v2f zb2; PK_ADD(zb2, xb2, nmu2); \
    v2f wa2; PK_MUL(wa2, ma2, iD2); \
    v2f wb2; PK_MUL(wb2, mb2, iD2); \
    v2f ta2; PK_MUL(ta2, wa2, za2); \
    v2f tb2; PK_MUL(tb2, wb2, zb2); \
    PK_FMA(quadA, ta2, za2); \
    PK_FMA(quadB, tb2, zb2); \
    v2f u0, u1, u2v, u3, u4, u5; \
    PK_MUL(u0, wa2, a0); PK_MUL(u1, wa2, a1); PK_MUL(u2v, wa2, a2); \
    PK_MUL(u3, wa2, a3); PK_MUL(u4, wa2, a4); PK_MUL(u5, wa2, a5); \
    PK_FMA(PA[0],  u0, a0); \
    PK_FMA(PA[1],  u1, a0); PK_FMA(PA[2],  u1, a1); \
    PK_FMA(PA[3],  u2v, a0); PK_FMA(PA[4],  u2v, a1); PK_FMA(PA[5],  u2v, a2); \
    PK_FMA(PA[6],  u3, a0); PK_FMA(PA[7],  u3, a1); PK_FMA(PA[8],  u3, a2); PK_FMA(PA[9],  u3, a3); \
    PK_FMA(PA[10], u4, a0); PK_FMA(PA[11], u4, a1); PK_FMA(PA[12], u4, a2); PK_FMA(PA[13], u4, a3); PK_FMA(PA[14], u4, a4); \
    PK_FMA(PA[15], u5, a0); PK_FMA(PA[16], u5, a1); PK_FMA(PA[17], u5, a2); PK_FMA(PA[18], u5, a3); PK_FMA(PA[19], u5, a4); PK_FMA(PA[20], u5, a5); \
    PK_FMA(qA[0], ta2, a0); PK_FMA(qA[1], ta2, a1); PK_FMA(qA[2], ta2, a2); \
    PK_FMA(qA[3], ta2, a3); PK_FMA(qA[4], ta2, a4); PK_FMA(qA[5], ta2, a5); \
    PK_MUL(u0, wb2, a0); PK_MUL(u1, wb2, a1); PK_MUL(u2v, wb2, a2); \
    PK_MUL(u3, wb2, a3); PK_MUL(u4, wb2, a4); PK_MUL(u5, wb2, a5); \
    PK_FMA(PB[0],  u0, a0); \
    PK_FMA(PB[1],  u1, a0); PK_FMA(PB[2],  u1, a1); \
    PK_FMA(PB[3],  u2v, a0); PK_FMA(PB[4],  u2v, a1); PK_FMA(PB[5],  u2v, a2); \
    PK_FMA(PB[6],  u3, a0); PK_FMA(PB[7],  u3, a1); PK_FMA(PB[8],  u3, a2); PK_FMA(PB[9],  u3, a3); \
    PK_FMA(PB[10], u4, a0); PK_FMA(PB[11], u4, a1); PK_FMA(PB[12], u4, a2); PK_FMA(PB[13], u4, a3); PK_FMA(PB[14], u4, a4); \
    PK_FMA(PB[15], u5, a0); PK_FMA(PB[16], u5, a1); PK_FMA(PB[17], u5, a2); PK_FMA(PB[18], u5, a3); PK_FMA(PB[19], u5, a4); PK_FMA(PB[20], u5, a5); \
    PK_FMA(qB[0], tb2, a0); PK_FMA(qB[1], tb2, a1); PK_FMA(qB[2], tb2, a2); \
    PK_FMA(qB[3], tb2, a3); PK_FMA(qB[4], tb2, a4); PK_FMA(qB[5], tb2, a5); \
} while (0)

__global__ __launch_bounds__(256, 3) void k_accum(
        const float4* __restrict__ Xt4, const unsigned* __restrict__ JbT,
        const float* __restrict__ A, const float* __restrict__ MU,
        const float* __restrict__ logD, const float* __restrict__ PI,
        float* __restrict__ scores, float* __restrict__ Pq) {
    __shared__ v2f srec[200 * 8];       // 12800 B records; aliased as merge slab
    float* smem = (float*)srec;
    float4* smf4 = (float4*)srec;
    const int k   = blockIdx.x >> 4;    // 16 btiles of 128 samples
    const int tid = threadIdx.x;
    const int s   = tid & 63;
    const int h   = tid >> 6;           // d-quarter 0..3
    const int b0  = (blockIdx.x & 15) * 128 + s;
    const int b1  = b0 + 64;

    v2f PA[21], qA[6], quadA;
    v2f PB[21], qB[6], quadB;
    #pragma unroll
    for (int t = 0; t < 21; ++t) { PA[t].x = 0.f; PA[t].y = 0.f; PB[t].x = 0.f; PB[t].y = 0.f; }
    #pragma unroll
    for (int t = 0; t < 6; ++t) { qA[t].x = 0.f; qA[t].y = 0.f; qB[t].x = 0.f; qB[t].y = 0.f; }
    quadA.x = 0.f; quadA.y = 0.f; quadB.x = 0.f; quadB.y = 0.f;
    int noba = 0, nobb = 0;

    for (int c = 0; c < 2; ++c) {
        const int dbase = c ? 384 : 0;
        const int npair = c ? 200 : 192;
        __syncthreads();                 // all quarters done reading old records
        for (int p = tid; p < npair; p += 256) {
            const int d0 = dbase + 2 * p;
            const float* ar0 = A + ((size_t)k * D_FT + d0) * 6;
            const float* ar1 = ar0 + 6;
            float iD0 = expf(-logD[(size_t)k * D_FT + d0]);
            float iD1 = expf(-logD[(size_t)k * D_FT + d0 + 1]);
            float4 f0, f1, f2, f3;
            f0.x = ar0[0]; f0.y = ar1[0]; f0.z = ar0[1]; f0.w = ar1[1];
            f1.x = ar0[2]; f1.y = ar1[2]; f1.z = ar0[3]; f1.w = ar1[3];
            f2.x = ar0[4]; f2.y = ar1[4]; f2.z = ar0[5]; f2.w = ar1[5];
            f3.x = iD0; f3.y = iD1;
            f3.z = -MU[(size_t)k * D_FT + d0];
            f3.w = -MU[(size_t)k * D_FT + d0 + 1];
            smf4[(size_t)p * 4 + 0] = f0;
            smf4[(size_t)p * 4 + 1] = f1;
            smf4[(size_t)p * 4 + 2] = f2;
            smf4[(size_t)p * 4 + 3] = f3;
        }
        __syncthreads();

        const int wb = (c ? 12 : 0) + 3 * h;
        for (int w = wb; w < wb + 3; ++w) {
            const unsigned mwa = JbT[(size_t)w * B_N + b0];
            const unsigned mwb = JbT[(size_t)w * B_N + b1];
            noba += __popc(mwa);
            nobb += __popc(mwb);
            const int plb = w * 16 - (dbase >> 1);   // local pair base
            const float4* xp = Xt4 + (size_t)(w * 8) * B_N + b0;
            #pragma unroll 2
            for (int g = 0; g < 8; ++g) {
                float4 xva = xp[(size_t)g * B_N];
                float4 xvb = xp[(size_t)g * B_N + 64];
                ACC_PAIR2(plb + 2 * g,     g * 4,     xva.x, xva.y, xvb.x, xvb.y);
                ACC_PAIR2(plb + 2 * g + 1, g * 4 + 2, xva.z, xva.w, xvb.z, xvb.w);
            }
        }
        if (c == 1 && h == 3) {  // tail word 24: bits 0..15 valid
            const unsigned mwa = JbT[(size_t)24 * B_N + b0];
            const unsigned mwb = JbT[(size_t)24 * B_N + b1];
            noba += __popc(mwa);
            nobb += __popc(mwb);
            const int plb = 24 * 16 - 192;           // = 192
            const float4* xp = Xt4 + (size_t)(24 * 8) * B_N + b0;
            #pragma unroll
            for (int g = 0; g < 4; ++g) {
                float4 xva = xp[(size_t)g * B_N];
                float4 xvb = xp[(size_t)g * B_N + 64];
                ACC_PAIR2(plb + 2 * g,     g * 4,     xva.x, xva.y, xvb.x, xvb.y);
                ACC_PAIR2(plb + 2 * g + 1, g * 4 + 2, xva.z, xva.w, xvb.z, xvb.w);
            }
        }
    }

    // horizontal add of packed halves
    float Pa[21], qa[6], quada, Pb[21], qb[6], quadb;
    #pragma unroll
    for (int t = 0; t < 21; ++t) { Pa[t] = PA[t].x + PA[t].y; Pb[t] = PB[t].x + PB[t].y; }
    #pragma unroll
    for (int t = 0; t < 6; ++t) { qa[t] = qA[t].x + qA[t].y; qb[t] = qB[t].x + qB[t].y; }
    quada = quadA.x + quadA.y;
    quadb = quadB.x + quadB.y;

    __syncthreads();                     // records dead; slab aliases them
    float* red = smem;                   // 64 x 33 slab, conflict-free
    #define SLAB_WR(P_, Q_, QU_, NB_) do { float* o = &red[s * 33]; \
        _Pragma("unroll") for (int t = 0; t < 21; ++t) o[t] = P_[t]; \
        _Pragma("unroll") for (int t = 0; t < 6; ++t) o[21 + t] = Q_[t]; \
        o[27] = QU_; o[28] = (float)(NB_); } while (0)
    #define SLAB_ADD(P_, Q_, QU_, NB_) do { const float* o = &red[s * 33]; \
        _Pragma("unroll") for (int t = 0; t < 21; ++t) P_[t] += o[t]; \
        _Pragma("unroll") for (int t = 0; t < 6; ++t) Q_[t] += o[21 + t]; \
        QU_ += o[27]; NB_ += (int)o[28]; } while (0)

    // phase A: sample b0 totals -> quarter 0
    if (h == 1) SLAB_WR(Pa, qa, quada, noba);
    __syncthreads();
    if (h == 0) SLAB_ADD(Pa, qa, quada, noba);
    __syncthreads();
    if (h == 3) SLAB_WR(Pa, qa, quada, noba);
    __syncthreads();
    if (h == 2) SLAB_ADD(Pa, qa, quada, noba);
    __syncthreads();
    if (h == 2) SLAB_WR(Pa, qa, quada, noba);
    __syncthreads();
    if (h == 0) SLAB_ADD(Pa, qa, quada, noba);
    __syncthreads();
    // phase B: sample b1 totals -> quarter 1
    if (h == 0) SLAB_WR(Pb, qb, quadb, nobb);
    __syncthreads();
    if (h == 1) SLAB_ADD(Pb, qb, quadb, nobb);
    __syncthreads();
    if (h == 2) SLAB_WR(Pb, qb, quadb, nobb);
    __syncthreads();
    if (h == 3) SLAB_ADD(Pb, qb, quadb, nobb);
    __syncthreads();
    if (h == 3) SLAB_WR(Pb, qb, quadb, nobb);
    __syncthreads();
    if (h == 1) SLAB_ADD(Pb, qb, quadb, nobb);

    if (h == 0)
        epilogue(Pa, qa, quada, (float)noba, k, b0, PI, scores, Pq);
    else if (h == 1)
        epilogue(Pb, qb, quadb, (float)nobb, k, b1, PI, scores, Pq);
}

// ---------- KD: fused argmax + latent solve (wave 0 only) + output write ----------
__global__ __launch_bounds__(256) void k_outsel(
        const float* __restrict__ scores, const float* __restrict__ Pq,
        const float* __restrict__ A, const float* __restrict__ MU,
        const float* __restrict__ logD, float* __restrict__ out) {
    __shared__ float smz[6];
    __shared__ float sLz[21];
    __shared__ int sc;
    const int b = blockIdx.x;
    const int tid = threadIdx.x;

    if (tid < 64) {
        float best = scores[b];
        int bc = 0;
        for (int kk = 1; kk < K_N; ++kk) {
            float sv = scores[(size_t)kk * B_N + b];
            if (sv > best) { best = sv; bc = kk; }
        }

        float Pm[21], qv[6];
        const float* pq = Pq + (size_t)bc * 27 * B_N + b;
        #pragma unroll
        for (int t = 0; t < 21; ++t) Pm[t] = pq[(size_t)t * B_N];
        #pragma unroll
        for (int t = 0; t < 6; ++t) qv[t] = pq[(size_t)(21 + t) * B_N];

        float Lm[21], rd[6], dummy;
        chol6(Pm, Lm, rd, &dummy);

        float y[6];
        #pragma unroll
        for (int j = 0; j < 6; ++j) {
            float sv = qv[j];
            #pragma unroll
            for (int m = 0; m < j; ++m) sv -= Lm[IDX(j,m)] * y[m];
            y[j] = sv * rd[j];
        }
        float mz[6];
        #pragma unroll
        for (int ii = 5; ii >= 0; --ii) {
            float sv = y[ii];
            #pragma unroll
            for (int j = ii + 1; j < 6; ++j) sv -= Lm[IDX(j,ii)] * mz[j];
            mz[ii] = sv * rd[ii];
        }
        float Li[21];
        #pragma unroll
        for (int j = 0; j < 6; ++j) {
            Li[IDX(j,j)] = rd[j];
            #pragma unroll
            for (int i = j + 1; i < 6; ++i) {
                float sv = 0.f;
                #pragma unroll
                for (int m = j; m < i; ++m) sv += Lm[IDX(i,m)] * Li[IDX(m,j)];
                Li[IDX(i,j)] = -sv * rd[i];
            }
        }
        float cov[21];
        #pragma unroll
        for (int i = 0; i < 6; ++i) {
            #pragma unroll
            for (int j = 0; j <= i; ++j) {
                float sv = 0.f;
                #pragma unroll
                for (int m = i; m < 6; ++m) sv += Li[IDX(m,i)] * Li[IDX(m,j)];
                cov[IDX(i,j)] = sv;
            }
        }
        float Lz[21], rd2[6];
        chol6(cov, Lz, rd2, &dummy);

        if (tid == 0) {
            sc = bc;
            out[OUT_PW + b] = 1.0f;
            #pragma unroll
            for (int t = 0; t < 6; ++t) smz[t] = mz[t];
            #pragma unroll
            for (int t = 0; t < 21; ++t) sLz[t] = Lz[t];
        }
    }
    __syncthreads();
    const int c = sc;

    for (int d = tid; d < D_FT; d += 256) {
        const float* ar = A + ((size_t)c * D_FT + d) * 6;
        float a[6];
        #pragma unroll
        for (int i = 0; i < 6; ++i) a[i] = ar[i];
        float mu = MU[(size_t)c * D_FT + d];
        float ld = logD[(size_t)c * D_FT + d];
        float m = mu;
        #pragma unroll
        for (int i = 0; i < 6; ++i) m += a[i] * smz[i];
        out[OUT_M + (size_t)b * D_FT + d] = m;
        out[OUT_D + (size_t)b * D_FT + d] = expf(ld);
        float* ao = out + OUT_A + ((size_t)b * D_FT + d) * 6;
        #pragma unroll
        for (int j = 0; j < 6; ++j) {
            float sv = 0.f;
            #pragma unroll
            for (int i = j; i < 6; ++i) sv += a[i] * sLz[IDX(i,j)];
            ao[j] = sv;
        }
    }
}

extern "C" void kernel_launch(void* const* d_in, const int* in_sizes, int n_in,
                              void* d_out, int out_size, void* d_ws, size_t ws_size,
                              hipStream_t stream) {
    (void)in_sizes; (void)n_in; (void)out_size; (void)ws_size;
    const float* X    = (const float*)d_in[0];
    const int*   J    = (const int*)d_in[1];
    const float* MU   = (const float*)d_in[2];
    const float* A    = (const float*)d_in[3];
    const float* logD = (const float*)d_in[4];
    const float* PI   = (const float*)d_in[5];
    float* out = (float*)d_out;
    float* ws  = (float*)d_ws;

    float*    scores = ws + WS_SCORES;
    float*    Pq     = ws + WS_PQ;
    float4*   Xt4    = (float4*)(ws + WS_XT);
    unsigned* JbT    = (unsigned*)(ws + WS_JBT);

    k_prep<<<512, 1024, 0, stream>>>(X, J, Xt4, JbT);

    k_jld<<<K_N * 8, 256, 0, stream>>>(logD, JbT, scores);

    k_accum<<<16 * K_N, 256, 0, stream>>>(Xt4, JbT, A, MU, logD, PI, scores, Pq);

    k_outsel<<<B_N, 256, 0, stream>>>(scores, Pq, A, MU, logD, out);
}